// Round 3
// baseline (365.923 us; speedup 1.0000x reference)
//
#include <hip/hip_runtime.h>

typedef __attribute__((ext_vector_type(8))) short s16x8;
typedef __attribute__((ext_vector_type(4))) float f32x4;
typedef unsigned short u16;

#define B_SZ 2
#define SEQ 8192
#define KD 1024
#define HD 1024
#define RK 16
#define CH 256
#define NCH 64          // total chunks = B_SZ * SEQ/CH
static constexpr float LR_SC = 0.02f;     // TTT_LR * SCALING
static constexpr float SCALE_OUT = 2.0f;  // SCALING

// ---------- helpers ----------
__device__ __forceinline__ u16 f2b(float f) {
  union { float f; unsigned int u; } c; c.f = f;
  unsigned int u = c.u;
  unsigned int r = (u + 0x7fffu + ((u >> 16) & 1u)) >> 16;
  return (u16)r;
}
__device__ __forceinline__ float b2f(u16 v) {
  union { unsigned int u; float f; } c; c.u = ((unsigned int)v) << 16; return c.f;
}
__device__ __forceinline__ void async16(const u16* g, u16* l) {
  __builtin_amdgcn_global_load_lds((const __attribute__((address_space(1))) void*)g,
                                   (__attribute__((address_space(3))) void*)l, 16, 0, 0);
}

// ---------- fp32 -> bf16 convert ----------
__global__ __launch_bounds__(256) void cvt_bf16(const float* __restrict__ src,
                                                u16* __restrict__ dst, int n) {
  int i = (blockIdx.x * 256 + threadIdx.x) * 4;
  if (i < n) {
    float4 v = *(const float4*)(src + i);
    ushort4 o; o.x = f2b(v.x); o.y = f2b(v.y); o.z = f2b(v.z); o.w = f2b(v.w);
    *(ushort4*)(dst + i) = o;
  }
}

// ---------- WpAT[r][k] = sum_h init_A[h][r] * Wp[h][k]  (bf16 out) ----------
__global__ __launch_bounds__(256) void wpat_kernel(const float* __restrict__ initA,
                                                   const float* __restrict__ Wp,
                                                   u16* __restrict__ WpAT) {
  int t = threadIdx.x;
  int k = blockIdx.x * 64 + (t & 63);
  int rq = t >> 6;                 // 0..3 -> r = rq*4..rq*4+3
  float a0 = 0.f, a1 = 0.f, a2 = 0.f, a3 = 0.f;
  #pragma unroll 8
  for (int h = 0; h < HD; h++) {
    float w = Wp[(size_t)h * KD + k];
    float4 a = *(const float4*)(initA + h * RK + rq * 4);
    a0 += w * a.x; a1 += w * a.y; a2 += w * a.z; a3 += w * a.w;
  }
  WpAT[(size_t)(rq * 4 + 0) * KD + k] = f2b(a0);
  WpAT[(size_t)(rq * 4 + 1) * KD + k] = f2b(a1);
  WpAT[(size_t)(rq * 4 + 2) * KD + k] = f2b(a2);
  WpAT[(size_t)(rq * 4 + 3) * KD + k] = f2b(a3);
}

// ---------- x -> bf16; LN of own row -> shb[row-1]; row s==0 zeroes shb[batch_last] ----------
__global__ __launch_bounds__(256) void ln_shift(const float* __restrict__ x,
                                                const float* __restrict__ gamma,
                                                const float* __restrict__ beta,
                                                u16* __restrict__ xb,
                                                u16* __restrict__ shb) {
  int row = blockIdx.x;           // 0..16383
  int t = threadIdx.x;
  int s = row & (SEQ - 1);
  const float* xr = x + (size_t)row * KD;
  float4 v = *(const float4*)(xr + t * 4);
  ushort4 o; o.x = f2b(v.x); o.y = f2b(v.y); o.z = f2b(v.z); o.w = f2b(v.w);
  *(ushort4*)(xb + (size_t)row * KD + t * 4) = o;

  if (s == 0) {  // block-uniform: zero the batch's last shifted row, skip LN
    ushort4 z; z.x = 0; z.y = 0; z.z = 0; z.w = 0;
    *(ushort4*)(shb + ((size_t)row + SEQ - 1) * KD + t * 4) = z;
    return;
  }
  float s1 = v.x + v.y + v.z + v.w;
  float s2 = v.x * v.x + v.y * v.y + v.z * v.z + v.w * v.w;
  #pragma unroll
  for (int off = 32; off > 0; off >>= 1) {
    s1 += __shfl_down(s1, off);
    s2 += __shfl_down(s2, off);
  }
  __shared__ float red[8];
  int wave = t >> 6, lane = t & 63;
  if (lane == 0) { red[wave * 2] = s1; red[wave * 2 + 1] = s2; }
  __syncthreads();
  float sum = red[0] + red[2] + red[4] + red[6];
  float ssq = red[1] + red[3] + red[5] + red[7];
  float mu = sum * (1.0f / KD);
  float var = ssq * (1.0f / KD) - mu * mu;
  float rstd = rsqrtf(var + 1e-5f);
  float4 g = *(const float4*)(gamma + t * 4);
  float4 bb = *(const float4*)(beta + t * 4);
  ushort4 so;
  so.x = f2b((v.x - mu) * rstd * g.x + bb.x);
  so.y = f2b((v.y - mu) * rstd * g.y + bb.y);
  so.z = f2b((v.z - mu) * rstd * g.z + bb.z);
  so.w = f2b((v.w - mu) * rstd * g.w + bb.w);
  *(ushort4*)(shb + (size_t)(row - 1) * KD + t * 4) = so;
}

// ---------- out = xb @ Wb^T + mid2 @ Aeff^T (fp32 output, LoRA K-extension) ----------
// LDS XOR-swizzle: stage lane (row r, chunk p) holds global k-chunk p^((r>>1)&3);
// fragment read for quad q at row r reads LDS chunk q^((r>>1)&3). 8-way -> 2-way conflict.
__global__ __launch_bounds__(256, 2) void gemm_fused(const u16* __restrict__ A,
                                                     const u16* __restrict__ Bm,
                                                     const u16* __restrict__ mid2,
                                                     const u16* __restrict__ Aef,
                                                     float* __restrict__ C) {
  constexpr int BM = 128, BN = 128, BK = 32, N = HD, Kd = KD;
  __shared__ u16 As[BM * BK];
  __shared__ u16 Bs[BN * BK];
  int tid = threadIdx.x;
  int lane = tid & 63, wave = tid >> 6;
  int m0 = blockIdx.y * BM, n0 = blockIdx.x * BN;
  int wm = (wave >> 1) * 64, wn = (wave & 1) * 64;
  int lr = lane & 15;
  int swz = (((lane >> 4) ^ ((lr >> 1) & 3)) & 3) * 8;   // swizzled k-offset (u16 units)
  f32x4 acc[4][4] = {};

  const u16* gbase; u16* lbase;
  if (wave < 2) { gbase = A + (size_t)(m0 + wave * 64) * Kd; lbase = As + wave * 64 * BK; }
  else          { gbase = Bm + (size_t)(n0 + (wave - 2) * 64) * Kd; lbase = Bs + (wave - 2) * 64 * BK; }
  int srow = lane >> 2;
  int scol = (((lane & 3) ^ ((srow >> 1) & 3)) & 3) * 8;
  const u16* gsrc = gbase + (size_t)srow * Kd + scol;

  for (int k0 = 0; k0 < Kd; k0 += BK) {
    #pragma unroll
    for (int i = 0; i < 4; i++)
      async16(gsrc + (size_t)i * 16 * Kd, lbase + i * 16 * BK);
    gsrc += BK;
    __syncthreads();
    s16x8 af[4], bfr[4];
    #pragma unroll
    for (int i = 0; i < 4; i++) af[i] = *(const s16x8*)(As + (wm + i * 16 + lr) * BK + swz);
    #pragma unroll
    for (int j = 0; j < 4; j++) bfr[j] = *(const s16x8*)(Bs + (wn + j * 16 + lr) * BK + swz);
    #pragma unroll
    for (int i = 0; i < 4; i++)
      #pragma unroll
      for (int j = 0; j < 4; j++)
        acc[i][j] = __builtin_amdgcn_mfma_f32_16x16x32_bf16(af[i], bfr[j], acc[i][j], 0, 0, 0);
    __syncthreads();
  }

  // LoRA K-extension: one zero-padded k-step. chunk uniform per block.
  {
    int chunk = blockIdx.y >> 1;
    const u16* abase = Aef + (size_t)chunk * (HD * RK);
    int klane = lane >> 4;        // only 0,1 carry real k
    s16x8 am2[4], bn2[4];
    #pragma unroll
    for (int i = 0; i < 4; i++) {
      if (klane < 2)
        am2[i] = *(const s16x8*)(mid2 + (size_t)(m0 + wm + i * 16 + lr) * RK + klane * 8);
      else { s16x8 z = {}; am2[i] = z; }
    }
    #pragma unroll
    for (int j = 0; j < 4; j++) {
      if (klane < 2)
        bn2[j] = *(const s16x8*)(abase + (size_t)(n0 + wn + j * 16 + lr) * RK + klane * 8);
      else { s16x8 z = {}; bn2[j] = z; }
    }
    #pragma unroll
    for (int i = 0; i < 4; i++)
      #pragma unroll
      for (int j = 0; j < 4; j++)
        acc[i][j] = __builtin_amdgcn_mfma_f32_16x16x32_bf16(am2[i], bn2[j], acc[i][j], 0, 0, 0);
  }

  int rb = (lane >> 4) * 4, cc = lane & 15;
  #pragma unroll
  for (int i = 0; i < 4; i++)
    #pragma unroll
    for (int j = 0; j < 4; j++)
      #pragma unroll
      for (int p = 0; p < 4; p++)
        C[(size_t)(m0 + wm + i * 16 + rb + p) * N + (n0 + wn + j * 16 + cc)] = acc[i][j][p];
}

// ---------- rank-16 MFMA: O[M x 16] = X[M x 1024] @ W[16 x 1024]^T ----------
// z=0: pin = xb @ initB^T ; z=1: per = shb @ WpAT^T (= V @ init_A)
__global__ __launch_bounds__(256) void rank16_proj(const u16* __restrict__ xb,
                                                   const u16* __restrict__ shb,
                                                   const u16* __restrict__ iBb,
                                                   const u16* __restrict__ WpAT,
                                                   float* __restrict__ pin,
                                                   float* __restrict__ per) {
  const u16* X; const u16* W; float* O;
  if (blockIdx.z == 0) { X = xb; W = iBb; O = pin; }
  else                 { X = shb; W = WpAT; O = per; }
  int wave = threadIdx.x >> 6, lane = threadIdx.x & 63;
  int m0 = (blockIdx.x * 4 + wave) * 16;
  int lr = lane & 15, lk = (lane >> 4) * 8;
  const u16* xp = X + (size_t)(m0 + lr) * KD + lk;
  const u16* wp = W + (size_t)lr * KD + lk;
  f32x4 acc = {};
  #pragma unroll 4
  for (int k0 = 0; k0 < KD; k0 += 32) {
    s16x8 a = *(const s16x8*)xp;
    s16x8 b = *(const s16x8*)wp;
    acc = __builtin_amdgcn_mfma_f32_16x16x32_bf16(a, b, acc, 0, 0, 0);
    xp += 32; wp += 32;
  }
  int rb = (lane >> 4) * 4, cc = lane & 15;
  #pragma unroll
  for (int p = 0; p < 4; p++)
    O[(size_t)(m0 + rb + p) * RK + cc] = acc[p];
}

// ---------- mid2 = 2 * (xb @ Beff[chunk]^T), bf16 out ----------
__global__ __launch_bounds__(256) void rank16_mid(const u16* __restrict__ xb,
                                                  const u16* __restrict__ Bef,
                                                  u16* __restrict__ mid2) {
  int wave = threadIdx.x >> 6, lane = threadIdx.x & 63;
  int m0 = (blockIdx.x * 4 + wave) * 16;
  int chunk = m0 >> 8;
  int lr = lane & 15, lk = (lane >> 4) * 8;
  const u16* xp = xb + (size_t)(m0 + lr) * KD + lk;
  const u16* wp = Bef + (size_t)chunk * (RK * KD) + (size_t)lr * KD + lk;
  f32x4 acc = {};
  #pragma unroll 4
  for (int k0 = 0; k0 < KD; k0 += 32) {
    s16x8 a = *(const s16x8*)xp;
    s16x8 b = *(const s16x8*)wp;
    acc = __builtin_amdgcn_mfma_f32_16x16x32_bf16(a, b, acc, 0, 0, 0);
    xp += 32; wp += 32;
  }
  int rb = (lane >> 4) * 4, cc = lane & 15;
  #pragma unroll
  for (int p = 0; p < 4; p++)
    mid2[(size_t)(m0 + rb + p) * RK + cc] = f2b(SCALE_OUT * acc[p]);
}

// ---------- z=0: G[c][r][k] = sum_cc shb[cc][k]*pin[cc][r]
// ---------- z=1: dB[c][r][k] = sum_cc per[cc][r]*xb[cc][k]
__global__ __launch_bounds__(256) void gk_kernel(const u16* __restrict__ xb,
                                                 const u16* __restrict__ shb,
                                                 const float* __restrict__ pin,
                                                 const float* __restrict__ per,
                                                 float* __restrict__ G,
                                                 float* __restrict__ dB) {
  int tile = blockIdx.x;    // 0..3
  int chunk = blockIdx.y;
  int which = blockIdx.z;
  int t = threadIdx.x;
  __shared__ float P[CH * RK];
  const float* psrc = which ? per : pin;
  for (int i = t; i < 1024; i += 256)
    *(float4*)&P[i * 4] = *(const float4*)&psrc[(size_t)chunk * 4096 + i * 4];
  __syncthreads();
  float acc[16];
  #pragma unroll
  for (int j = 0; j < 16; j++) acc[j] = 0.f;
  int col = tile * 256 + t;
  const u16* src = (which ? xb : shb) + (size_t)chunk * CH * KD + col;
  for (int c = 0; c < 256; c++) {
    float v = b2f(src[(size_t)c * 1024]);
    const float4* pr = (const float4*)&P[c * 16];
    #pragma unroll
    for (int q = 0; q < 4; q++) {
      float4 p = pr[q];
      acc[q*4+0] += v * p.x; acc[q*4+1] += v * p.y;
      acc[q*4+2] += v * p.z; acc[q*4+3] += v * p.w;
    }
  }
  float* o = (which ? dB : G) + (size_t)chunk * 16384 + col;
  #pragma unroll
  for (int j = 0; j < 16; j++) o[(size_t)j * 1024] = acc[j];
}

// ---------- exclusive cumsum over chunks, scaled by lr ----------
__global__ __launch_bounds__(256) void cumsum_kernel(const float* __restrict__ G,
                                                     const float* __restrict__ dB,
                                                     u16* __restrict__ rawG,
                                                     float* __restrict__ rawB) {
  int idx = blockIdx.x * 256 + threadIdx.x;  // 0..65535
  int which = idx >> 15;
  int rem = idx & 32767;
  int b = rem >> 14;
  int e = rem & 16383;
  size_t base = (size_t)b * 32 * 16384 + e;
  if (which == 0) {
    float run = 0.f;
    for (int i = 0; i < 32; i++) {
      size_t off = base + (size_t)i * 16384;
      float nv = G[off];
      rawG[off] = f2b(LR_SC * run);
      run += nv;
    }
  } else {
    float run = 0.f;
    for (int i = 0; i < 32; i++) {
      size_t off = base + (size_t)i * 16384;
      float nv = dB[off];
      rawB[off] = LR_SC * run;
      run += nv;
    }
  }
}

// ---------- rawA[c][h][r] = sum_k Wpb[h][k] * rawG[c][r][k]  (fp32 out) ----------
__global__ __launch_bounds__(256) void dagemm(const u16* __restrict__ Wpb,
                                              const u16* __restrict__ rawG,
                                              float* __restrict__ rawA) {
  int wave = threadIdx.x >> 6, lane = threadIdx.x & 63;
  int m0 = (blockIdx.x * 4 + wave) * 16;   // h-tile
  int chunk = blockIdx.y;
  int lr = lane & 15, lk = (lane >> 4) * 8;
  const u16* ap = Wpb + (size_t)(m0 + lr) * KD + lk;
  const u16* bp = rawG + (size_t)chunk * 16384 + (size_t)lr * KD + lk;
  f32x4 acc = {};
  #pragma unroll 4
  for (int k0 = 0; k0 < KD; k0 += 32) {
    s16x8 a = *(const s16x8*)ap;
    s16x8 b = *(const s16x8*)bp;
    acc = __builtin_amdgcn_mfma_f32_16x16x32_bf16(a, b, acc, 0, 0, 0);
    ap += 32; bp += 32;
  }
  int rb = (lane >> 4) * 4, cc = lane & 15;
  #pragma unroll
  for (int p = 0; p < 4; p++)
    rawA[(size_t)chunk * 16384 + (size_t)(m0 + rb + p) * RK + cc] = acc[p];
}

// ---------- joint norm clip coefficient ----------
__global__ __launch_bounds__(256) void coef_kernel(const float* __restrict__ rawA,
                                                   const float* __restrict__ rawB,
                                                   float* __restrict__ coef) {
  int chunk = blockIdx.x, t = threadIdx.x;
  const float* a = rawA + (size_t)chunk * 16384;
  const float* b = rawB + (size_t)chunk * 16384;
  float s = 0.f;
  for (int i = t * 4; i < 16384; i += 1024) {
    float4 v = *(const float4*)(a + i);
    s += v.x*v.x + v.y*v.y + v.z*v.z + v.w*v.w;
    float4 w = *(const float4*)(b + i);
    s += w.x*w.x + w.y*w.y + w.z*w.z + w.w*w.w;
  }
  #pragma unroll
  for (int off = 32; off > 0; off >>= 1) s += __shfl_down(s, off);
  __shared__ float red[4];
  int wave = t >> 6, lane = t & 63;
  if (lane == 0) red[wave] = s;
  __syncthreads();
  if (t == 0) {
    float tot = red[0] + red[1] + red[2] + red[3];
    float n = sqrtf(tot);
    coef[chunk] = fminf(1.0f / (n + 1e-6f), 1.0f);
  }
}

// ---------- A_eff / B_eff -> bf16 ----------
__global__ __launch_bounds__(256) void eff_kernel(const float* __restrict__ initA,
                                                  const float* __restrict__ initB,
                                                  const float* __restrict__ rawA,
                                                  const float* __restrict__ rawB,
                                                  const float* __restrict__ coef,
                                                  u16* __restrict__ Aef,
                                                  u16* __restrict__ Bef) {
  int idx = blockIdx.x * 256 + threadIdx.x;   // 0..524287, x4 elements
  int which = idx >> 18;
  int rem = idx & 262143;
  int chunk = rem >> 12;
  int e = (rem & 4095) * 4;
  float cf = coef[chunk];
  const float* ini = which ? initB : initA;
  const float* raw = (which ? rawB : rawA) + (size_t)chunk * 16384;
  u16* out = (which ? Bef : Aef) + (size_t)chunk * 16384;
  float4 iv = *(const float4*)(ini + e);
  float4 rv = *(const float4*)(raw + e);
  ushort4 r;
  r.x = f2b(iv.x - rv.x * cf); r.y = f2b(iv.y - rv.y * cf);
  r.z = f2b(iv.z - rv.z * cf); r.w = f2b(iv.w - rv.w * cf);
  *(ushort4*)(out + e) = r;
}

extern "C" void kernel_launch(void* const* d_in, const int* in_sizes, int n_in,
                              void* d_out, int out_size, void* d_ws, size_t ws_size,
                              hipStream_t stream) {
  (void)in_sizes; (void)n_in; (void)out_size; (void)ws_size;
  const float* x     = (const float*)d_in[0];
  const float* Wb    = (const float*)d_in[1];
  const float* initA = (const float*)d_in[2];
  const float* initB = (const float*)d_in[3];
  const float* gamma = (const float*)d_in[4];
  const float* beta  = (const float*)d_in[5];
  const float* Wp    = (const float*)d_in[6];
  float* out = (float*)d_out;

  char* ws = (char*)d_ws;
  size_t off = 0;
  auto alloc = [&](size_t bytes) -> void* {
    void* p = ws + off;
    off = (off + bytes + 255) & ~(size_t)255;
    return p;
  };
  const size_t ROWS = (size_t)B_SZ * SEQ;  // 16384
  u16* xb    = (u16*)alloc(ROWS * KD * 2);
  u16* shb   = (u16*)alloc(ROWS * KD * 2);
  u16* Wbb   = (u16*)alloc((size_t)HD * KD * 2);
  u16* Wpb   = (u16*)alloc((size_t)HD * KD * 2);
  u16* iBb   = (u16*)alloc((size_t)RK * KD * 2);
  u16* WpAT  = (u16*)alloc((size_t)RK * KD * 2);
  float* pin = (float*)alloc((size_t)NCH * CH * RK * 4);
  float* per = (float*)alloc((size_t)NCH * CH * RK * 4);
  float* G   = (float*)alloc((size_t)NCH * 16384 * 4);
  float* dB  = (float*)alloc((size_t)NCH * 16384 * 4);
  u16* rawG  = (u16*)alloc((size_t)NCH * 16384 * 2);
  float* rawB= (float*)alloc((size_t)NCH * 16384 * 4);
  float* rawA= (float*)alloc((size_t)NCH * 16384 * 4);
  float* cf  = (float*)alloc(NCH * 4);
  u16* Aef   = (u16*)alloc((size_t)NCH * 16384 * 2);
  u16* Bef   = (u16*)alloc((size_t)NCH * 16384 * 2);
  u16* mid2  = (u16*)alloc(ROWS * RK * 2);

  cvt_bf16<<<1024, 256, 0, stream>>>(Wb, Wbb, HD * KD);
  cvt_bf16<<<1024, 256, 0, stream>>>(Wp, Wpb, HD * KD);
  cvt_bf16<<<16, 256, 0, stream>>>(initB, iBb, RK * KD);
  wpat_kernel<<<16, 256, 0, stream>>>(initA, Wp, WpAT);
  ln_shift<<<ROWS, 256, 0, stream>>>(x, gamma, beta, xb, shb);
  rank16_proj<<<dim3(256, 1, 2), 256, 0, stream>>>(xb, shb, iBb, WpAT, pin, per);
  gk_kernel<<<dim3(4, NCH, 2), 256, 0, stream>>>(xb, shb, pin, per, G, dB);
  cumsum_kernel<<<256, 256, 0, stream>>>(G, dB, rawG, rawB);
  dagemm<<<dim3(16, NCH), 256, 0, stream>>>(Wpb, rawG, rawA);
  coef_kernel<<<NCH, 256, 0, stream>>>(rawA, rawB, cf);
  eff_kernel<<<2048, 256, 0, stream>>>(initA, initB, rawA, rawB, cf, Aef, Bef);
  rank16_mid<<<256, 256, 0, stream>>>(xb, Bef, mid2);
  gemm_fused<<<dim3(HD / 128, ROWS / 128), 256, 0, stream>>>(xb, Wbb, mid2, Aef, out);
}

// Round 4
// 320.753 us; speedup vs baseline: 1.1408x; 1.1408x over previous
//
#include <hip/hip_runtime.h>

typedef __attribute__((ext_vector_type(8))) short s16x8;
typedef __attribute__((ext_vector_type(4))) float f32x4;
typedef unsigned short u16;

#define B_SZ 2
#define SEQ 8192
#define KD 1024
#define HD 1024
#define RK 16
#define CH 256
#define NCH 64          // total chunks = B_SZ * SEQ/CH
static constexpr float LR_SC = 0.02f;     // TTT_LR * SCALING
static constexpr float SCALE_OUT = 2.0f;  // SCALING

// ---------- helpers ----------
__device__ __forceinline__ u16 f2b(float f) {
  union { float f; unsigned int u; } c; c.f = f;
  unsigned int u = c.u;
  unsigned int r = (u + 0x7fffu + ((u >> 16) & 1u)) >> 16;
  return (u16)r;
}
__device__ __forceinline__ float b2f(u16 v) {
  union { unsigned int u; float f; } c; c.u = ((unsigned int)v) << 16; return c.f;
}
__device__ __forceinline__ void async16(const u16* g, u16* l) {
  __builtin_amdgcn_global_load_lds((const __attribute__((address_space(1))) void*)g,
                                   (__attribute__((address_space(3))) void*)l, 16, 0, 0);
}

// ---------- fp32 -> bf16 convert ----------
__global__ __launch_bounds__(256) void cvt_bf16(const float* __restrict__ src,
                                                u16* __restrict__ dst, int n) {
  int i = (blockIdx.x * 256 + threadIdx.x) * 4;
  if (i < n) {
    float4 v = *(const float4*)(src + i);
    ushort4 o; o.x = f2b(v.x); o.y = f2b(v.y); o.z = f2b(v.z); o.w = f2b(v.w);
    *(ushort4*)(dst + i) = o;
  }
}

// ---------- WpAT partials: part[hseg][k][r] = sum_{h in seg} initA[h][r]*Wp[h][k] ----------
__global__ __launch_bounds__(256) void wpat_part(const float* __restrict__ initA,
                                                 const float* __restrict__ Wp,
                                                 float* __restrict__ part) {
  int t = threadIdx.x;
  int k = blockIdx.x * 256 + t;
  int hseg = blockIdx.y;
  __shared__ float Asm[256 * 16];
  for (int i = t; i < 1024; i += 256)
    *(float4*)&Asm[i * 4] = *(const float4*)&initA[(size_t)hseg * 4096 + i * 4];
  __syncthreads();
  float acc[16];
  #pragma unroll
  for (int j = 0; j < 16; j++) acc[j] = 0.f;
  const float* wp = Wp + (size_t)hseg * 256 * KD + k;
  #pragma unroll 4
  for (int hh = 0; hh < 256; hh++) {
    float w = wp[(size_t)hh * KD];
    const float4* ar = (const float4*)&Asm[hh * 16];
    #pragma unroll
    for (int q = 0; q < 4; q++) {
      float4 a = ar[q];
      acc[q*4+0] += w * a.x; acc[q*4+1] += w * a.y;
      acc[q*4+2] += w * a.z; acc[q*4+3] += w * a.w;
    }
  }
  float* o = part + ((size_t)hseg * 1024 + k) * 16;
  #pragma unroll
  for (int q = 0; q < 4; q++) {
    float4 r; r.x = acc[q*4]; r.y = acc[q*4+1]; r.z = acc[q*4+2]; r.w = acc[q*4+3];
    *(float4*)&o[q * 4] = r;
  }
}

// ---------- WpAT[r][k] = sum_seg part[seg][k][r]  (bf16 out) ----------
__global__ __launch_bounds__(256) void wpat_reduce(const float* __restrict__ part,
                                                   u16* __restrict__ WpAT) {
  int idx = blockIdx.x * 256 + threadIdx.x;   // 0..16383
  int k = idx & 1023, r = idx >> 10;
  float s = part[((size_t)0 * 1024 + k) * 16 + r]
          + part[((size_t)1 * 1024 + k) * 16 + r]
          + part[((size_t)2 * 1024 + k) * 16 + r]
          + part[((size_t)3 * 1024 + k) * 16 + r];
  WpAT[(size_t)r * KD + k] = f2b(s);
}

// ---------- x -> bf16; LN of own row -> shb[row-1]; row s==0 zeroes shb[batch_last] ----------
__global__ __launch_bounds__(256) void ln_shift(const float* __restrict__ x,
                                                const float* __restrict__ gamma,
                                                const float* __restrict__ beta,
                                                u16* __restrict__ xb,
                                                u16* __restrict__ shb) {
  int row = blockIdx.x;           // 0..16383
  int t = threadIdx.x;
  int s = row & (SEQ - 1);
  const float* xr = x + (size_t)row * KD;
  float4 v = *(const float4*)(xr + t * 4);
  ushort4 o; o.x = f2b(v.x); o.y = f2b(v.y); o.z = f2b(v.z); o.w = f2b(v.w);
  *(ushort4*)(xb + (size_t)row * KD + t * 4) = o;

  if (s == 0) {  // block-uniform: zero the batch's last shifted row, skip LN
    ushort4 z; z.x = 0; z.y = 0; z.z = 0; z.w = 0;
    *(ushort4*)(shb + ((size_t)row + SEQ - 1) * KD + t * 4) = z;
    return;
  }
  float s1 = v.x + v.y + v.z + v.w;
  float s2 = v.x * v.x + v.y * v.y + v.z * v.z + v.w * v.w;
  #pragma unroll
  for (int off = 32; off > 0; off >>= 1) {
    s1 += __shfl_down(s1, off);
    s2 += __shfl_down(s2, off);
  }
  __shared__ float red[8];
  int wave = t >> 6, lane = t & 63;
  if (lane == 0) { red[wave * 2] = s1; red[wave * 2 + 1] = s2; }
  __syncthreads();
  float sum = red[0] + red[2] + red[4] + red[6];
  float ssq = red[1] + red[3] + red[5] + red[7];
  float mu = sum * (1.0f / KD);
  float var = ssq * (1.0f / KD) - mu * mu;
  float rstd = rsqrtf(var + 1e-5f);
  float4 g = *(const float4*)(gamma + t * 4);
  float4 bb = *(const float4*)(beta + t * 4);
  ushort4 so;
  so.x = f2b((v.x - mu) * rstd * g.x + bb.x);
  so.y = f2b((v.y - mu) * rstd * g.y + bb.y);
  so.z = f2b((v.z - mu) * rstd * g.z + bb.z);
  so.w = f2b((v.w - mu) * rstd * g.w + bb.w);
  *(ushort4*)(shb + (size_t)(row - 1) * KD + t * 4) = so;
}

// ---------- out = xb @ Wb^T + mid2 @ Aeff^T (fp32 output, LoRA K-extension) ----------
// LDS XOR-swizzle: stage lane (row r, chunk p) holds global k-chunk p^((r>>1)&3);
// fragment read for quad q at row r reads LDS chunk q^((r>>1)&3). 8-way -> 2-way conflict.
__global__ __launch_bounds__(256, 2) void gemm_fused(const u16* __restrict__ A,
                                                     const u16* __restrict__ Bm,
                                                     const u16* __restrict__ mid2,
                                                     const u16* __restrict__ Aef,
                                                     float* __restrict__ C) {
  constexpr int BM = 128, BN = 128, BK = 32, N = HD, Kd = KD;
  __shared__ u16 As[BM * BK];
  __shared__ u16 Bs[BN * BK];
  int tid = threadIdx.x;
  int lane = tid & 63, wave = tid >> 6;
  int m0 = blockIdx.y * BM, n0 = blockIdx.x * BN;
  int wm = (wave >> 1) * 64, wn = (wave & 1) * 64;
  int lr = lane & 15;
  int swz = (((lane >> 4) ^ ((lr >> 1) & 3)) & 3) * 8;   // swizzled k-offset (u16 units)
  f32x4 acc[4][4] = {};

  const u16* gbase; u16* lbase;
  if (wave < 2) { gbase = A + (size_t)(m0 + wave * 64) * Kd; lbase = As + wave * 64 * BK; }
  else          { gbase = Bm + (size_t)(n0 + (wave - 2) * 64) * Kd; lbase = Bs + (wave - 2) * 64 * BK; }
  int srow = lane >> 2;
  int scol = (((lane & 3) ^ ((srow >> 1) & 3)) & 3) * 8;
  const u16* gsrc = gbase + (size_t)srow * Kd + scol;

  for (int k0 = 0; k0 < Kd; k0 += BK) {
    #pragma unroll
    for (int i = 0; i < 4; i++)
      async16(gsrc + (size_t)i * 16 * Kd, lbase + i * 16 * BK);
    gsrc += BK;
    __syncthreads();
    s16x8 af[4], bfr[4];
    #pragma unroll
    for (int i = 0; i < 4; i++) af[i] = *(const s16x8*)(As + (wm + i * 16 + lr) * BK + swz);
    #pragma unroll
    for (int j = 0; j < 4; j++) bfr[j] = *(const s16x8*)(Bs + (wn + j * 16 + lr) * BK + swz);
    #pragma unroll
    for (int i = 0; i < 4; i++)
      #pragma unroll
      for (int j = 0; j < 4; j++)
        acc[i][j] = __builtin_amdgcn_mfma_f32_16x16x32_bf16(af[i], bfr[j], acc[i][j], 0, 0, 0);
    __syncthreads();
  }

  // LoRA K-extension: one zero-padded k-step. chunk uniform per block.
  {
    int chunk = blockIdx.y >> 1;
    const u16* abase = Aef + (size_t)chunk * (HD * RK);
    int klane = lane >> 4;        // only 0,1 carry real k
    s16x8 am2[4], bn2[4];
    #pragma unroll
    for (int i = 0; i < 4; i++) {
      if (klane < 2)
        am2[i] = *(const s16x8*)(mid2 + (size_t)(m0 + wm + i * 16 + lr) * RK + klane * 8);
      else { s16x8 z = {}; am2[i] = z; }
    }
    #pragma unroll
    for (int j = 0; j < 4; j++) {
      if (klane < 2)
        bn2[j] = *(const s16x8*)(abase + (size_t)(n0 + wn + j * 16 + lr) * RK + klane * 8);
      else { s16x8 z = {}; bn2[j] = z; }
    }
    #pragma unroll
    for (int i = 0; i < 4; i++)
      #pragma unroll
      for (int j = 0; j < 4; j++)
        acc[i][j] = __builtin_amdgcn_mfma_f32_16x16x32_bf16(am2[i], bn2[j], acc[i][j], 0, 0, 0);
  }

  int rb = (lane >> 4) * 4, cc = lane & 15;
  #pragma unroll
  for (int i = 0; i < 4; i++)
    #pragma unroll
    for (int j = 0; j < 4; j++)
      #pragma unroll
      for (int p = 0; p < 4; p++)
        C[(size_t)(m0 + wm + i * 16 + rb + p) * N + (n0 + wn + j * 16 + cc)] = acc[i][j][p];
}

// ---------- rank-16 MFMA: O[M x 16] = X[M x 1024] @ W[16 x 1024]^T ----------
// z=0: pin = xb @ initB^T ; z=1: per = shb @ WpAT^T (= V @ init_A)
__global__ __launch_bounds__(256) void rank16_proj(const u16* __restrict__ xb,
                                                   const u16* __restrict__ shb,
                                                   const u16* __restrict__ iBb,
                                                   const u16* __restrict__ WpAT,
                                                   float* __restrict__ pin,
                                                   float* __restrict__ per) {
  const u16* X; const u16* W; float* O;
  if (blockIdx.z == 0) { X = xb; W = iBb; O = pin; }
  else                 { X = shb; W = WpAT; O = per; }
  int wave = threadIdx.x >> 6, lane = threadIdx.x & 63;
  int m0 = (blockIdx.x * 4 + wave) * 16;
  int lr = lane & 15, lk = (lane >> 4) * 8;
  const u16* xp = X + (size_t)(m0 + lr) * KD + lk;
  const u16* wp = W + (size_t)lr * KD + lk;
  f32x4 acc = {};
  #pragma unroll 4
  for (int k0 = 0; k0 < KD; k0 += 32) {
    s16x8 a = *(const s16x8*)xp;
    s16x8 b = *(const s16x8*)wp;
    acc = __builtin_amdgcn_mfma_f32_16x16x32_bf16(a, b, acc, 0, 0, 0);
    xp += 32; wp += 32;
  }
  int rb = (lane >> 4) * 4, cc = lane & 15;
  #pragma unroll
  for (int p = 0; p < 4; p++)
    O[(size_t)(m0 + rb + p) * RK + cc] = acc[p];
}

// ---------- mid2 = 2 * (xb @ Beff[chunk]^T), bf16 out ----------
__global__ __launch_bounds__(256) void rank16_mid(const u16* __restrict__ xb,
                                                  const u16* __restrict__ Bef,
                                                  u16* __restrict__ mid2) {
  int wave = threadIdx.x >> 6, lane = threadIdx.x & 63;
  int m0 = (blockIdx.x * 4 + wave) * 16;
  int chunk = m0 >> 8;
  int lr = lane & 15, lk = (lane >> 4) * 8;
  const u16* xp = xb + (size_t)(m0 + lr) * KD + lk;
  const u16* wp = Bef + (size_t)chunk * (RK * KD) + (size_t)lr * KD + lk;
  f32x4 acc = {};
  #pragma unroll 4
  for (int k0 = 0; k0 < KD; k0 += 32) {
    s16x8 a = *(const s16x8*)xp;
    s16x8 b = *(const s16x8*)wp;
    acc = __builtin_amdgcn_mfma_f32_16x16x32_bf16(a, b, acc, 0, 0, 0);
    xp += 32; wp += 32;
  }
  int rb = (lane >> 4) * 4, cc = lane & 15;
  #pragma unroll
  for (int p = 0; p < 4; p++)
    mid2[(size_t)(m0 + rb + p) * RK + cc] = f2b(SCALE_OUT * acc[p]);
}

// ---------- z=0: G[c][r][k] = sum_cc shb[cc][k]*pin[cc][r]
// ---------- z=1: dB[c][r][k] = sum_cc per[cc][r]*xb[cc][k]
__global__ __launch_bounds__(256) void gk_kernel(const u16* __restrict__ xb,
                                                 const u16* __restrict__ shb,
                                                 const float* __restrict__ pin,
                                                 const float* __restrict__ per,
                                                 float* __restrict__ G,
                                                 float* __restrict__ dB) {
  int tile = blockIdx.x;    // 0..3
  int chunk = blockIdx.y;
  int which = blockIdx.z;
  int t = threadIdx.x;
  __shared__ float P[CH * RK];
  const float* psrc = which ? per : pin;
  for (int i = t; i < 1024; i += 256)
    *(float4*)&P[i * 4] = *(const float4*)&psrc[(size_t)chunk * 4096 + i * 4];
  __syncthreads();
  float acc[16];
  #pragma unroll
  for (int j = 0; j < 16; j++) acc[j] = 0.f;
  int col = tile * 256 + t;
  const u16* src = (which ? xb : shb) + (size_t)chunk * CH * KD + col;
  for (int c = 0; c < 256; c++) {
    float v = b2f(src[(size_t)c * 1024]);
    const float4* pr = (const float4*)&P[c * 16];
    #pragma unroll
    for (int q = 0; q < 4; q++) {
      float4 p = pr[q];
      acc[q*4+0] += v * p.x; acc[q*4+1] += v * p.y;
      acc[q*4+2] += v * p.z; acc[q*4+3] += v * p.w;
    }
  }
  float* o = (which ? dB : G) + (size_t)chunk * 16384 + col;
  #pragma unroll
  for (int j = 0; j < 16; j++) o[(size_t)j * 1024] = acc[j];
}

// ---------- exclusive cumsum over chunks, scaled by lr ----------
__global__ __launch_bounds__(256) void cumsum_kernel(const float* __restrict__ G,
                                                     const float* __restrict__ dB,
                                                     u16* __restrict__ rawG,
                                                     float* __restrict__ rawB) {
  int idx = blockIdx.x * 256 + threadIdx.x;  // 0..65535
  int which = idx >> 15;
  int rem = idx & 32767;
  int b = rem >> 14;
  int e = rem & 16383;
  size_t base = (size_t)b * 32 * 16384 + e;
  if (which == 0) {
    float run = 0.f;
    for (int i = 0; i < 32; i++) {
      size_t off = base + (size_t)i * 16384;
      float nv = G[off];
      rawG[off] = f2b(LR_SC * run);
      run += nv;
    }
  } else {
    float run = 0.f;
    for (int i = 0; i < 32; i++) {
      size_t off = base + (size_t)i * 16384;
      float nv = dB[off];
      rawB[off] = LR_SC * run;
      run += nv;
    }
  }
}

// ---------- rawA[c][h][r] = sum_k Wpb[h][k] * rawG[c][r][k]  (fp32 out) ----------
__global__ __launch_bounds__(256) void dagemm(const u16* __restrict__ Wpb,
                                              const u16* __restrict__ rawG,
                                              float* __restrict__ rawA) {
  int wave = threadIdx.x >> 6, lane = threadIdx.x & 63;
  int m0 = (blockIdx.x * 4 + wave) * 16;   // h-tile
  int chunk = blockIdx.y;
  int lr = lane & 15, lk = (lane >> 4) * 8;
  const u16* ap = Wpb + (size_t)(m0 + lr) * KD + lk;
  const u16* bp = rawG + (size_t)chunk * 16384 + (size_t)lr * KD + lk;
  f32x4 acc = {};
  #pragma unroll 4
  for (int k0 = 0; k0 < KD; k0 += 32) {
    s16x8 a = *(const s16x8*)ap;
    s16x8 b = *(const s16x8*)bp;
    acc = __builtin_amdgcn_mfma_f32_16x16x32_bf16(a, b, acc, 0, 0, 0);
    ap += 32; bp += 32;
  }
  int rb = (lane >> 4) * 4, cc = lane & 15;
  #pragma unroll
  for (int p = 0; p < 4; p++)
    rawA[(size_t)chunk * 16384 + (size_t)(m0 + rb + p) * RK + cc] = acc[p];
}

// ---------- joint norm clip coefficient ----------
__global__ __launch_bounds__(256) void coef_kernel(const float* __restrict__ rawA,
                                                   const float* __restrict__ rawB,
                                                   float* __restrict__ coef) {
  int chunk = blockIdx.x, t = threadIdx.x;
  const float* a = rawA + (size_t)chunk * 16384;
  const float* b = rawB + (size_t)chunk * 16384;
  float s = 0.f;
  for (int i = t * 4; i < 16384; i += 1024) {
    float4 v = *(const float4*)(a + i);
    s += v.x*v.x + v.y*v.y + v.z*v.z + v.w*v.w;
    float4 w = *(const float4*)(b + i);
    s += w.x*w.x + w.y*w.y + w.z*w.z + w.w*w.w;
  }
  #pragma unroll
  for (int off = 32; off > 0; off >>= 1) s += __shfl_down(s, off);
  __shared__ float red[4];
  int wave = t >> 6, lane = t & 63;
  if (lane == 0) red[wave] = s;
  __syncthreads();
  if (t == 0) {
    float tot = red[0] + red[1] + red[2] + red[3];
    float n = sqrtf(tot);
    coef[chunk] = fminf(1.0f / (n + 1e-6f), 1.0f);
  }
}

// ---------- A_eff / B_eff -> bf16 ----------
__global__ __launch_bounds__(256) void eff_kernel(const float* __restrict__ initA,
                                                  const float* __restrict__ initB,
                                                  const float* __restrict__ rawA,
                                                  const float* __restrict__ rawB,
                                                  const float* __restrict__ coef,
                                                  u16* __restrict__ Aef,
                                                  u16* __restrict__ Bef) {
  int idx = blockIdx.x * 256 + threadIdx.x;   // 0..524287, x4 elements
  int which = idx >> 18;
  int rem = idx & 262143;
  int chunk = rem >> 12;
  int e = (rem & 4095) * 4;
  float cf = coef[chunk];
  const float* ini = which ? initB : initA;
  const float* raw = (which ? rawB : rawA) + (size_t)chunk * 16384;
  u16* out = (which ? Bef : Aef) + (size_t)chunk * 16384;
  float4 iv = *(const float4*)(ini + e);
  float4 rv = *(const float4*)(raw + e);
  ushort4 r;
  r.x = f2b(iv.x - rv.x * cf); r.y = f2b(iv.y - rv.y * cf);
  r.z = f2b(iv.z - rv.z * cf); r.w = f2b(iv.w - rv.w * cf);
  *(ushort4*)(out + e) = r;
}

extern "C" void kernel_launch(void* const* d_in, const int* in_sizes, int n_in,
                              void* d_out, int out_size, void* d_ws, size_t ws_size,
                              hipStream_t stream) {
  (void)in_sizes; (void)n_in; (void)out_size; (void)ws_size;
  const float* x     = (const float*)d_in[0];
  const float* Wb    = (const float*)d_in[1];
  const float* initA = (const float*)d_in[2];
  const float* initB = (const float*)d_in[3];
  const float* gamma = (const float*)d_in[4];
  const float* beta  = (const float*)d_in[5];
  const float* Wp    = (const float*)d_in[6];
  float* out = (float*)d_out;

  char* ws = (char*)d_ws;
  size_t off = 0;
  auto alloc = [&](size_t bytes) -> void* {
    void* p = ws + off;
    off = (off + bytes + 255) & ~(size_t)255;
    return p;
  };
  const size_t ROWS = (size_t)B_SZ * SEQ;  // 16384
  u16* xb    = (u16*)alloc(ROWS * KD * 2);
  u16* shb   = (u16*)alloc(ROWS * KD * 2);
  u16* Wbb   = (u16*)alloc((size_t)HD * KD * 2);
  u16* Wpb   = (u16*)alloc((size_t)HD * KD * 2);
  u16* iBb   = (u16*)alloc((size_t)RK * KD * 2);
  u16* WpAT  = (u16*)alloc((size_t)RK * KD * 2);
  float* wpart = (float*)alloc((size_t)4 * KD * RK * 4);
  float* pin = (float*)alloc((size_t)NCH * CH * RK * 4);
  float* per = (float*)alloc((size_t)NCH * CH * RK * 4);
  float* G   = (float*)alloc((size_t)NCH * 16384 * 4);
  float* dB  = (float*)alloc((size_t)NCH * 16384 * 4);
  u16* rawG  = (u16*)alloc((size_t)NCH * 16384 * 2);
  float* rawB= (float*)alloc((size_t)NCH * 16384 * 4);
  float* rawA= (float*)alloc((size_t)NCH * 16384 * 4);
  float* cf  = (float*)alloc(NCH * 4);
  u16* Aef   = (u16*)alloc((size_t)NCH * 16384 * 2);
  u16* Bef   = (u16*)alloc((size_t)NCH * 16384 * 2);
  u16* mid2  = (u16*)alloc(ROWS * RK * 2);

  cvt_bf16<<<1024, 256, 0, stream>>>(Wb, Wbb, HD * KD);
  cvt_bf16<<<1024, 256, 0, stream>>>(Wp, Wpb, HD * KD);
  cvt_bf16<<<16, 256, 0, stream>>>(initB, iBb, RK * KD);
  wpat_part<<<dim3(4, 4), 256, 0, stream>>>(initA, Wp, wpart);
  wpat_reduce<<<64, 256, 0, stream>>>(wpart, WpAT);
  ln_shift<<<ROWS, 256, 0, stream>>>(x, gamma, beta, xb, shb);
  rank16_proj<<<dim3(256, 1, 2), 256, 0, stream>>>(xb, shb, iBb, WpAT, pin, per);
  gk_kernel<<<dim3(4, NCH, 2), 256, 0, stream>>>(xb, shb, pin, per, G, dB);
  cumsum_kernel<<<256, 256, 0, stream>>>(G, dB, rawG, rawB);
  dagemm<<<dim3(16, NCH), 256, 0, stream>>>(Wpb, rawG, rawA);
  coef_kernel<<<NCH, 256, 0, stream>>>(rawA, rawB, cf);
  eff_kernel<<<2048, 256, 0, stream>>>(initA, initB, rawA, rawB, cf, Aef, Bef);
  rank16_mid<<<256, 256, 0, stream>>>(xb, Bef, mid2);
  gemm_fused<<<dim3(HD / 128, ROWS / 128), 256, 0, stream>>>(xb, Wbb, mid2, Aef, out);
}

// Round 5
// 313.954 us; speedup vs baseline: 1.1655x; 1.0217x over previous
//
#include <hip/hip_runtime.h>

typedef __attribute__((ext_vector_type(8))) short s16x8;
typedef __attribute__((ext_vector_type(4))) float f32x4;
typedef unsigned short u16;

#define B_SZ 2
#define SEQ 8192
#define KD 1024
#define HD 1024
#define RK 16
#define CH 256
#define NCH 64          // total chunks = B_SZ * SEQ/CH
static constexpr float LR_SC = 0.02f;     // TTT_LR * SCALING
static constexpr float SCALE_OUT = 2.0f;  // SCALING

// ---------- helpers ----------
__device__ __forceinline__ u16 f2b(float f) {
  union { float f; unsigned int u; } c; c.f = f;
  unsigned int u = c.u;
  unsigned int r = (u + 0x7fffu + ((u >> 16) & 1u)) >> 16;
  return (u16)r;
}
__device__ __forceinline__ float b2f(u16 v) {
  union { unsigned int u; float f; } c; c.u = ((unsigned int)v) << 16; return c.f;
}
__device__ __forceinline__ void async16(const u16* g, u16* l) {
  __builtin_amdgcn_global_load_lds((const __attribute__((address_space(1))) void*)g,
                                   (__attribute__((address_space(3))) void*)l, 16, 0, 0);
}

// ---------- fp32 -> bf16 convert: Wb, Wp, initB in one dispatch ----------
__global__ __launch_bounds__(256) void cvt_all(const float* __restrict__ Wb,
                                               const float* __restrict__ Wp,
                                               const float* __restrict__ initB,
                                               u16* __restrict__ Wbb,
                                               u16* __restrict__ Wpb,
                                               u16* __restrict__ iBb) {
  int bid = blockIdx.x;
  const float* src; u16* dst; int base;
  if (bid < 1024)      { src = Wb;    dst = Wbb; base = bid; }
  else if (bid < 2048) { src = Wp;    dst = Wpb; base = bid - 1024; }
  else                 { src = initB; dst = iBb; base = bid - 2048; }
  int i = (base * 256 + threadIdx.x) * 4;
  float4 v = *(const float4*)(src + i);
  ushort4 o; o.x = f2b(v.x); o.y = f2b(v.y); o.z = f2b(v.z); o.w = f2b(v.w);
  *(ushort4*)(dst + i) = o;
}

// ---------- WpAT partials: part[hseg][k][r] = sum_{h in seg} initA[h][r]*Wp[h][k] ----------
__global__ __launch_bounds__(256) void wpat_part(const float* __restrict__ initA,
                                                 const float* __restrict__ Wp,
                                                 float* __restrict__ part) {
  int t = threadIdx.x;
  int k = blockIdx.x * 256 + t;
  int hseg = blockIdx.y;
  __shared__ float Asm[256 * 16];
  for (int i = t; i < 1024; i += 256)
    *(float4*)&Asm[i * 4] = *(const float4*)&initA[(size_t)hseg * 4096 + i * 4];
  __syncthreads();
  float acc[16];
  #pragma unroll
  for (int j = 0; j < 16; j++) acc[j] = 0.f;
  const float* wp = Wp + (size_t)hseg * 256 * KD + k;
  #pragma unroll 4
  for (int hh = 0; hh < 256; hh++) {
    float w = wp[(size_t)hh * KD];
    const float4* ar = (const float4*)&Asm[hh * 16];
    #pragma unroll
    for (int q = 0; q < 4; q++) {
      float4 a = ar[q];
      acc[q*4+0] += w * a.x; acc[q*4+1] += w * a.y;
      acc[q*4+2] += w * a.z; acc[q*4+3] += w * a.w;
    }
  }
  float* o = part + ((size_t)hseg * 1024 + k) * 16;
  #pragma unroll
  for (int q = 0; q < 4; q++) {
    float4 r; r.x = acc[q*4]; r.y = acc[q*4+1]; r.z = acc[q*4+2]; r.w = acc[q*4+3];
    *(float4*)&o[q * 4] = r;
  }
}

// ---------- WpAT[r][k] = sum_seg part[seg][k][r]  (bf16 out) ----------
__global__ __launch_bounds__(256) void wpat_reduce(const float* __restrict__ part,
                                                   u16* __restrict__ WpAT) {
  int idx = blockIdx.x * 256 + threadIdx.x;   // 0..16383
  int k = idx & 1023, r = idx >> 10;
  float s = part[((size_t)0 * 1024 + k) * 16 + r]
          + part[((size_t)1 * 1024 + k) * 16 + r]
          + part[((size_t)2 * 1024 + k) * 16 + r]
          + part[((size_t)3 * 1024 + k) * 16 + r];
  WpAT[(size_t)r * KD + k] = f2b(s);
}

// ---------- x -> bf16; LN of own row -> shb[row-1]; row s==0 zeroes shb[batch_last] ----------
__global__ __launch_bounds__(256) void ln_shift(const float* __restrict__ x,
                                                const float* __restrict__ gamma,
                                                const float* __restrict__ beta,
                                                u16* __restrict__ xb,
                                                u16* __restrict__ shb) {
  int row = blockIdx.x;           // 0..16383
  int t = threadIdx.x;
  int s = row & (SEQ - 1);
  const float* xr = x + (size_t)row * KD;
  float4 v = *(const float4*)(xr + t * 4);
  ushort4 o; o.x = f2b(v.x); o.y = f2b(v.y); o.z = f2b(v.z); o.w = f2b(v.w);
  *(ushort4*)(xb + (size_t)row * KD + t * 4) = o;

  if (s == 0) {  // block-uniform: zero the batch's last shifted row, skip LN
    ushort4 z; z.x = 0; z.y = 0; z.z = 0; z.w = 0;
    *(ushort4*)(shb + ((size_t)row + SEQ - 1) * KD + t * 4) = z;
    return;
  }
  float s1 = v.x + v.y + v.z + v.w;
  float s2 = v.x * v.x + v.y * v.y + v.z * v.z + v.w * v.w;
  #pragma unroll
  for (int off = 32; off > 0; off >>= 1) {
    s1 += __shfl_down(s1, off);
    s2 += __shfl_down(s2, off);
  }
  __shared__ float red[8];
  int wave = t >> 6, lane = t & 63;
  if (lane == 0) { red[wave * 2] = s1; red[wave * 2 + 1] = s2; }
  __syncthreads();
  float sum = red[0] + red[2] + red[4] + red[6];
  float ssq = red[1] + red[3] + red[5] + red[7];
  float mu = sum * (1.0f / KD);
  float var = ssq * (1.0f / KD) - mu * mu;
  float rstd = rsqrtf(var + 1e-5f);
  float4 g = *(const float4*)(gamma + t * 4);
  float4 bb = *(const float4*)(beta + t * 4);
  ushort4 so;
  so.x = f2b((v.x - mu) * rstd * g.x + bb.x);
  so.y = f2b((v.y - mu) * rstd * g.y + bb.y);
  so.z = f2b((v.z - mu) * rstd * g.z + bb.z);
  so.w = f2b((v.w - mu) * rstd * g.w + bb.w);
  *(ushort4*)(shb + (size_t)(row - 1) * KD + t * 4) = so;
}

// ---------- out = xb @ Wb^T + mid2 @ Aeff^T (fp32 output, LoRA K-extension) ----------
// BK=64, XCD-aware block swizzle (XCD q owns M-stripe q*16..q*16+15 -> A stripe fits its L2),
// 8-slot XOR LDS swizzle (slot ^= row&7): staging stays 128B-coalesced, reads 2-way (free).
__global__ __launch_bounds__(256, 2) void gemm_fused(const u16* __restrict__ A,
                                                     const u16* __restrict__ Bm,
                                                     const u16* __restrict__ mid2,
                                                     const u16* __restrict__ Aef,
                                                     float* __restrict__ C) {
  constexpr int BM = 128, BN = 128, BK = 64, N = HD, Kd = KD;
  __shared__ u16 As[BM * BK];
  __shared__ u16 Bs[BN * BK];
  int tid = threadIdx.x;
  int lane = tid & 63, wave = tid >> 6;
  // XCD swizzle: lb%8 = XCD; give XCD q a contiguous 16-row-band stripe.
  int lb = blockIdx.x + 8 * blockIdx.y;     // gridDim = (8,128)
  int q = lb & 7, t = lb >> 3;              // t: 0..127
  int mb = q * 16 + (t >> 3);
  int nb = t & 7;
  int m0 = mb * 128, n0 = nb * 128;
  int wm = (wave >> 1) * 64, wn = (wave & 1) * 64;
  int lr = lane & 15;
  int qd = lane >> 4;          // quad 0..3
  int sw = lr & 7;             // row-derived XOR key
  int slot0 = ((qd ^ sw) * 8);             // h=0 k-offset (u16)
  int slot1 = (((4 + qd) ^ sw) * 8);       // h=1
  f32x4 acc[4][4] = {};

  const u16* gbase; u16* lbase;
  if (wave < 2) { gbase = A + (size_t)(m0 + wave * 64) * Kd; lbase = As + wave * 64 * BK; }
  else          { gbase = Bm + (size_t)(n0 + (wave - 2) * 64) * Kd; lbase = Bs + (wave - 2) * 64 * BK; }
  int srow = lane >> 3;                       // 0..7
  int scol = ((lane & 7) ^ srow) * 8;         // swizzled global slot
  const u16* gsrc = gbase + (size_t)srow * Kd + scol;

  for (int k0 = 0; k0 < Kd; k0 += BK) {
    #pragma unroll
    for (int i = 0; i < 8; i++)
      async16(gsrc + (size_t)i * 8 * Kd, lbase + i * 512);
    gsrc += BK;
    __syncthreads();
    s16x8 af[4], bfr[4];
    // h = 0
    #pragma unroll
    for (int i = 0; i < 4; i++) af[i] = *(const s16x8*)(As + (wm + i * 16 + lr) * BK + slot0);
    #pragma unroll
    for (int j = 0; j < 4; j++) bfr[j] = *(const s16x8*)(Bs + (wn + j * 16 + lr) * BK + slot0);
    #pragma unroll
    for (int i = 0; i < 4; i++)
      #pragma unroll
      for (int j = 0; j < 4; j++)
        acc[i][j] = __builtin_amdgcn_mfma_f32_16x16x32_bf16(af[i], bfr[j], acc[i][j], 0, 0, 0);
    // h = 1
    #pragma unroll
    for (int i = 0; i < 4; i++) af[i] = *(const s16x8*)(As + (wm + i * 16 + lr) * BK + slot1);
    #pragma unroll
    for (int j = 0; j < 4; j++) bfr[j] = *(const s16x8*)(Bs + (wn + j * 16 + lr) * BK + slot1);
    #pragma unroll
    for (int i = 0; i < 4; i++)
      #pragma unroll
      for (int j = 0; j < 4; j++)
        acc[i][j] = __builtin_amdgcn_mfma_f32_16x16x32_bf16(af[i], bfr[j], acc[i][j], 0, 0, 0);
    __syncthreads();
  }

  // LoRA K-extension: one zero-padded k-step. chunk uniform per block.
  {
    int chunk = m0 >> 8;
    const u16* abase = Aef + (size_t)chunk * (HD * RK);
    int klane = lane >> 4;        // only 0,1 carry real k
    s16x8 am2[4], bn2[4];
    #pragma unroll
    for (int i = 0; i < 4; i++) {
      if (klane < 2)
        am2[i] = *(const s16x8*)(mid2 + (size_t)(m0 + wm + i * 16 + lr) * RK + klane * 8);
      else { s16x8 z = {}; am2[i] = z; }
    }
    #pragma unroll
    for (int j = 0; j < 4; j++) {
      if (klane < 2)
        bn2[j] = *(const s16x8*)(abase + (size_t)(n0 + wn + j * 16 + lr) * RK + klane * 8);
      else { s16x8 z = {}; bn2[j] = z; }
    }
    #pragma unroll
    for (int i = 0; i < 4; i++)
      #pragma unroll
      for (int j = 0; j < 4; j++)
        acc[i][j] = __builtin_amdgcn_mfma_f32_16x16x32_bf16(am2[i], bn2[j], acc[i][j], 0, 0, 0);
  }

  int rb = (lane >> 4) * 4, cc = lane & 15;
  #pragma unroll
  for (int i = 0; i < 4; i++)
    #pragma unroll
    for (int j = 0; j < 4; j++)
      #pragma unroll
      for (int p = 0; p < 4; p++)
        C[(size_t)(m0 + wm + i * 16 + rb + p) * N + (n0 + wn + j * 16 + cc)] = acc[i][j][p];
}

// ---------- rank-16 MFMA: O[M x 16] = X[M x 1024] @ W[16 x 1024]^T ----------
// z=0: pin = xb @ initB^T ; z=1: per = shb @ WpAT^T (= V @ init_A)
__global__ __launch_bounds__(256) void rank16_proj(const u16* __restrict__ xb,
                                                   const u16* __restrict__ shb,
                                                   const u16* __restrict__ iBb,
                                                   const u16* __restrict__ WpAT,
                                                   float* __restrict__ pin,
                                                   float* __restrict__ per) {
  const u16* X; const u16* W; float* O;
  if (blockIdx.z == 0) { X = xb; W = iBb; O = pin; }
  else                 { X = shb; W = WpAT; O = per; }
  int wave = threadIdx.x >> 6, lane = threadIdx.x & 63;
  int m0 = (blockIdx.x * 4 + wave) * 16;
  int lr = lane & 15, lk = (lane >> 4) * 8;
  const u16* xp = X + (size_t)(m0 + lr) * KD + lk;
  const u16* wp = W + (size_t)lr * KD + lk;
  f32x4 acc = {};
  #pragma unroll 4
  for (int k0 = 0; k0 < KD; k0 += 32) {
    s16x8 a = *(const s16x8*)xp;
    s16x8 b = *(const s16x8*)wp;
    acc = __builtin_amdgcn_mfma_f32_16x16x32_bf16(a, b, acc, 0, 0, 0);
    xp += 32; wp += 32;
  }
  int rb = (lane >> 4) * 4, cc = lane & 15;
  #pragma unroll
  for (int p = 0; p < 4; p++)
    O[(size_t)(m0 + rb + p) * RK + cc] = acc[p];
}

// ---------- mid2 = 2 * (xb @ Beff[chunk]^T), bf16 out ----------
__global__ __launch_bounds__(256) void rank16_mid(const u16* __restrict__ xb,
                                                  const u16* __restrict__ Bef,
                                                  u16* __restrict__ mid2) {
  int wave = threadIdx.x >> 6, lane = threadIdx.x & 63;
  int m0 = (blockIdx.x * 4 + wave) * 16;
  int chunk = m0 >> 8;
  int lr = lane & 15, lk = (lane >> 4) * 8;
  const u16* xp = xb + (size_t)(m0 + lr) * KD + lk;
  const u16* wp = Bef + (size_t)chunk * (RK * KD) + (size_t)lr * KD + lk;
  f32x4 acc = {};
  #pragma unroll 4
  for (int k0 = 0; k0 < KD; k0 += 32) {
    s16x8 a = *(const s16x8*)xp;
    s16x8 b = *(const s16x8*)wp;
    acc = __builtin_amdgcn_mfma_f32_16x16x32_bf16(a, b, acc, 0, 0, 0);
    xp += 32; wp += 32;
  }
  int rb = (lane >> 4) * 4, cc = lane & 15;
  #pragma unroll
  for (int p = 0; p < 4; p++)
    mid2[(size_t)(m0 + rb + p) * RK + cc] = f2b(SCALE_OUT * acc[p]);
}

// ---------- z=0: G[c][r][k] = sum_cc shb[cc][k]*pin[cc][r]
// ---------- z=1: dB[c][r][k] = sum_cc per[cc][r]*xb[cc][k]
__global__ __launch_bounds__(256) void gk_kernel(const u16* __restrict__ xb,
                                                 const u16* __restrict__ shb,
                                                 const float* __restrict__ pin,
                                                 const float* __restrict__ per,
                                                 float* __restrict__ G,
                                                 float* __restrict__ dB) {
  int tile = blockIdx.x;    // 0..3
  int chunk = blockIdx.y;
  int which = blockIdx.z;
  int t = threadIdx.x;
  __shared__ float P[CH * RK];
  const float* psrc = which ? per : pin;
  for (int i = t; i < 1024; i += 256)
    *(float4*)&P[i * 4] = *(const float4*)&psrc[(size_t)chunk * 4096 + i * 4];
  __syncthreads();
  float acc[16];
  #pragma unroll
  for (int j = 0; j < 16; j++) acc[j] = 0.f;
  int col = tile * 256 + t;
  const u16* src = (which ? xb : shb) + (size_t)chunk * CH * KD + col;
  for (int c = 0; c < 256; c++) {
    float v = b2f(src[(size_t)c * 1024]);
    const float4* pr = (const float4*)&P[c * 16];
    #pragma unroll
    for (int q = 0; q < 4; q++) {
      float4 p = pr[q];
      acc[q*4+0] += v * p.x; acc[q*4+1] += v * p.y;
      acc[q*4+2] += v * p.z; acc[q*4+3] += v * p.w;
    }
  }
  float* o = (which ? dB : G) + (size_t)chunk * 16384 + col;
  #pragma unroll
  for (int j = 0; j < 16; j++) o[(size_t)j * 1024] = acc[j];
}

// ---------- exclusive cumsum over chunks, scaled by lr ----------
__global__ __launch_bounds__(256) void cumsum_kernel(const float* __restrict__ G,
                                                     const float* __restrict__ dB,
                                                     u16* __restrict__ rawG,
                                                     float* __restrict__ rawB) {
  int idx = blockIdx.x * 256 + threadIdx.x;  // 0..65535
  int which = idx >> 15;
  int rem = idx & 32767;
  int b = rem >> 14;
  int e = rem & 16383;
  size_t base = (size_t)b * 32 * 16384 + e;
  if (which == 0) {
    float run = 0.f;
    for (int i = 0; i < 32; i++) {
      size_t off = base + (size_t)i * 16384;
      float nv = G[off];
      rawG[off] = f2b(LR_SC * run);
      run += nv;
    }
  } else {
    float run = 0.f;
    for (int i = 0; i < 32; i++) {
      size_t off = base + (size_t)i * 16384;
      float nv = dB[off];
      rawB[off] = LR_SC * run;
      run += nv;
    }
  }
}

// ---------- rawA[c][h][r] = sum_k Wpb[h][k] * rawG[c][r][k]  (fp32 out) ----------
__global__ __launch_bounds__(256) void dagemm(const u16* __restrict__ Wpb,
                                              const u16* __restrict__ rawG,
                                              float* __restrict__ rawA) {
  int wave = threadIdx.x >> 6, lane = threadIdx.x & 63;
  int m0 = (blockIdx.x * 4 + wave) * 16;   // h-tile
  int chunk = blockIdx.y;
  int lr = lane & 15, lk = (lane >> 4) * 8;
  const u16* ap = Wpb + (size_t)(m0 + lr) * KD + lk;
  const u16* bp = rawG + (size_t)chunk * 16384 + (size_t)lr * KD + lk;
  f32x4 acc = {};
  #pragma unroll 4
  for (int k0 = 0; k0 < KD; k0 += 32) {
    s16x8 a = *(const s16x8*)ap;
    s16x8 b = *(const s16x8*)bp;
    acc = __builtin_amdgcn_mfma_f32_16x16x32_bf16(a, b, acc, 0, 0, 0);
    ap += 32; bp += 32;
  }
  int rb = (lane >> 4) * 4, cc = lane & 15;
  #pragma unroll
  for (int p = 0; p < 4; p++)
    rawA[(size_t)chunk * 16384 + (size_t)(m0 + rb + p) * RK + cc] = acc[p];
}

// ---------- joint norm clip + A_eff/B_eff emit (fused) ----------
__global__ __launch_bounds__(256) void coef_eff(const float* __restrict__ initA,
                                                const float* __restrict__ initB,
                                                const float* __restrict__ rawA,
                                                const float* __restrict__ rawB,
                                                u16* __restrict__ Aef,
                                                u16* __restrict__ Bef) {
  int chunk = blockIdx.x, t = threadIdx.x;
  const float* a = rawA + (size_t)chunk * 16384;
  const float* b = rawB + (size_t)chunk * 16384;
  float s = 0.f;
  for (int i = t * 4; i < 16384; i += 1024) {
    float4 v = *(const float4*)(a + i);
    s += v.x*v.x + v.y*v.y + v.z*v.z + v.w*v.w;
    float4 w = *(const float4*)(b + i);
    s += w.x*w.x + w.y*w.y + w.z*w.z + w.w*w.w;
  }
  #pragma unroll
  for (int off = 32; off > 0; off >>= 1) s += __shfl_down(s, off);
  __shared__ float red[4];
  int wave = t >> 6, lane = t & 63;
  if (lane == 0) red[wave] = s;
  __syncthreads();
  float tot = red[0] + red[1] + red[2] + red[3];
  float cf = fminf(1.0f / (sqrtf(tot) + 1e-6f), 1.0f);
  u16* ao = Aef + (size_t)chunk * 16384;
  u16* bo = Bef + (size_t)chunk * 16384;
  for (int i = t * 4; i < 16384; i += 1024) {
    float4 iv = *(const float4*)(initA + i);
    float4 rv = *(const float4*)(a + i);
    ushort4 r;
    r.x = f2b(iv.x - rv.x * cf); r.y = f2b(iv.y - rv.y * cf);
    r.z = f2b(iv.z - rv.z * cf); r.w = f2b(iv.w - rv.w * cf);
    *(ushort4*)(ao + i) = r;
    float4 iw = *(const float4*)(initB + i);
    float4 rw = *(const float4*)(b + i);
    ushort4 rr;
    rr.x = f2b(iw.x - rw.x * cf); rr.y = f2b(iw.y - rw.y * cf);
    rr.z = f2b(iw.z - rw.z * cf); rr.w = f2b(iw.w - rw.w * cf);
    *(ushort4*)(bo + i) = rr;
  }
}

extern "C" void kernel_launch(void* const* d_in, const int* in_sizes, int n_in,
                              void* d_out, int out_size, void* d_ws, size_t ws_size,
                              hipStream_t stream) {
  (void)in_sizes; (void)n_in; (void)out_size; (void)ws_size;
  const float* x     = (const float*)d_in[0];
  const float* Wb    = (const float*)d_in[1];
  const float* initA = (const float*)d_in[2];
  const float* initB = (const float*)d_in[3];
  const float* gamma = (const float*)d_in[4];
  const float* beta  = (const float*)d_in[5];
  const float* Wp    = (const float*)d_in[6];
  float* out = (float*)d_out;

  char* ws = (char*)d_ws;
  size_t off = 0;
  auto alloc = [&](size_t bytes) -> void* {
    void* p = ws + off;
    off = (off + bytes + 255) & ~(size_t)255;
    return p;
  };
  const size_t ROWS = (size_t)B_SZ * SEQ;  // 16384
  u16* xb    = (u16*)alloc(ROWS * KD * 2);
  u16* shb   = (u16*)alloc(ROWS * KD * 2);
  u16* Wbb   = (u16*)alloc((size_t)HD * KD * 2);
  u16* Wpb   = (u16*)alloc((size_t)HD * KD * 2);
  u16* iBb   = (u16*)alloc((size_t)RK * KD * 2);
  u16* WpAT  = (u16*)alloc((size_t)RK * KD * 2);
  float* wpart = (float*)alloc((size_t)4 * KD * RK * 4);
  float* pin = (float*)alloc((size_t)NCH * CH * RK * 4);
  float* per = (float*)alloc((size_t)NCH * CH * RK * 4);
  float* G   = (float*)alloc((size_t)NCH * 16384 * 4);
  float* dB  = (float*)alloc((size_t)NCH * 16384 * 4);
  u16* rawG  = (u16*)alloc((size_t)NCH * 16384 * 2);
  float* rawB= (float*)alloc((size_t)NCH * 16384 * 4);
  float* rawA= (float*)alloc((size_t)NCH * 16384 * 4);
  u16* Aef   = (u16*)alloc((size_t)NCH * 16384 * 2);
  u16* Bef   = (u16*)alloc((size_t)NCH * 16384 * 2);
  u16* mid2  = (u16*)alloc(ROWS * RK * 2);

  cvt_all<<<2064, 256, 0, stream>>>(Wb, Wp, initB, Wbb, Wpb, iBb);
  wpat_part<<<dim3(4, 4), 256, 0, stream>>>(initA, Wp, wpart);
  wpat_reduce<<<64, 256, 0, stream>>>(wpart, WpAT);
  ln_shift<<<ROWS, 256, 0, stream>>>(x, gamma, beta, xb, shb);
  rank16_proj<<<dim3(256, 1, 2), 256, 0, stream>>>(xb, shb, iBb, WpAT, pin, per);
  gk_kernel<<<dim3(4, NCH, 2), 256, 0, stream>>>(xb, shb, pin, per, G, dB);
  cumsum_kernel<<<256, 256, 0, stream>>>(G, dB, rawG, rawB);
  dagemm<<<dim3(16, NCH), 256, 0, stream>>>(Wpb, rawG, rawA);
  coef_eff<<<NCH, 256, 0, stream>>>(initA, initB, rawA, rawB, Aef, Bef);
  rank16_mid<<<256, 256, 0, stream>>>(xb, Bef, mid2);
  gemm_fused<<<dim3(8, 128), 256, 0, stream>>>(xb, Wbb, mid2, Aef, out);
}